// Round 3
// baseline (303.955 us; speedup 1.0000x reference)
//
#include <hip/hip_runtime.h>
#include <math.h>

#define NB 1024
static constexpr float BN_INV = 0.99999500003749975f; // 1/sqrt(1+1e-5)

typedef __attribute__((ext_vector_type(8))) short short8;
typedef __attribute__((ext_vector_type(4))) short s16x4;
typedef __attribute__((ext_vector_type(4))) float f32x4;

__device__ inline short f2bf(float f) {
  union { float f; unsigned u; } v;
  v.f = f;
  unsigned u = v.u;
  u += 0x7fff + ((u >> 16) & 1); // RNE
  return (short)(u >> 16);
}

// ---------------- prepack: conv1/conv2/conv3 weights -> MFMA A-frag bf16,
// BN folded. conv1: scale folded into weights, shift into scsh[384..416).
__global__ void k_prepack(const float* __restrict__ c1w, const float* __restrict__ c1b,
                          const float* __restrict__ g1, const float* __restrict__ be1,
                          const float* __restrict__ c2w, const float* __restrict__ c2b,
                          const float* __restrict__ g2, const float* __restrict__ be2,
                          const float* __restrict__ c3w, const float* __restrict__ c3b,
                          const float* __restrict__ g3, const float* __restrict__ be3,
                          short* __restrict__ wp1, short* __restrict__ wp2,
                          short* __restrict__ wp3, float* __restrict__ scsh) {
  int i = blockIdx.x * 256 + threadIdx.x;
  int stride = gridDim.x * 256;
  // conv1: A[co][k] = w1[co][c=k][ky][kx] * g1[co] * BN_INV for k<3 else 0
  for (int e = i; e < 9216; e += stride) {
    int j = e & 7, lane = (e >> 3) & 63, ct = (e >> 9) & 1, off = e >> 10;
    int co = ct * 16 + (lane & 15), k = (lane >> 4) * 8 + j;
    float v = 0.f;
    if (k < 3) v = c1w[(co * 3 + k) * 9 + off] * g1[co] * BN_INV;
    wp1[e] = f2bf(v);
  }
  for (int e = i; e < 18432; e += stride) {
    int j = e & 7, lane = (e >> 3) & 63, ct = (e >> 9) & 3, off = e >> 11;
    int co = ct * 16 + (lane & 15), ci = (lane >> 4) * 8 + j;
    wp2[e] = f2bf(c2w[(co * 32 + ci) * 9 + off]);
  }
  for (int e = i; e < 73728; e += stride) {
    int j = e & 7, lane = (e >> 3) & 63, ct = (e >> 9) & 7, oh = e >> 12;
    int half = oh & 1, off = oh >> 1;
    int co = ct * 16 + (lane & 15), ci = half * 32 + (lane >> 4) * 8 + j;
    wp3[e] = f2bf(c3w[(co * 64 + ci) * 9 + off]);
  }
  if (i < 64) {
    float sc = g2[i] * BN_INV;
    scsh[i] = sc;
    scsh[64 + i] = sc * c2b[i] + be2[i];
  } else if (i < 192) {
    int c = i - 64;
    float sc = g3[c] * BN_INV;
    scsh[128 + c] = sc;
    scsh[256 + c] = sc * c3b[c] + be3[c];
  } else if (i < 224) {
    int c = i - 192;
    scsh[384 + c] = g1[c] * BN_INV * c1b[c] + be1[c];
  }
}

// ---------------- fused conv1+conv2+conv3 (per-batch-image block) -----------
// Blocks [0,1024): conv pipeline, all intermediates in LDS. conv1 via MFMA
// (3 input channels on K, zero-padded to 4; A zero-padded k>=4).
// Blocks [1024,1152): fr1_w f32 -> bf16 conversion (independent side work).
// LDS: inT [18*18][40] bf16 (25920 B) | union{ tile1 [34*34][4] bf16 (9248 B),
//                                              inT3 [10*10][72] bf16 (14400 B)}
// total 40320 B -> 4 blocks/CU; launch_bounds(256,4) pins VGPR<=128.
__global__ __launch_bounds__(256, 4) void k_convfused(
    const float* __restrict__ x, const short* __restrict__ wp1,
    const short* __restrict__ wp2, const short* __restrict__ wp3,
    const float* __restrict__ scsh, const float* __restrict__ fr1w,
    short* __restrict__ wfr1, short* __restrict__ out3 /* bf16 [B,2048] */) {
  __shared__ __align__(16) char smem[40320];
  const int tid = threadIdx.x;
  const int bx = blockIdx.x;

  if (bx >= NB) {
    // fr1_w: 512*2048 f32 -> bf16, two at a time, 128 blocks
    int i = (bx - NB) * 256 + tid;
    for (int e = i; e < 524288; e += 128 * 256) {
      float2 f = ((const float2*)fr1w)[e];
      unsigned lo = (unsigned)(unsigned short)f2bf(f.x);
      unsigned hi = (unsigned)(unsigned short)f2bf(f.y);
      ((unsigned*)wfr1)[e] = (hi << 16) | lo;
    }
    return;
  }

  short* inT = (short*)smem;             // conv1 out, padded, ch-padded to 40
  short* tile1 = (short*)(smem + 25920); // conv1 input bf16 [34][34][4]
  short* inT3 = (short*)(smem + 25920);  // conv2 out (phase 2+), aliases tile1

  const int b = bx;
  const int wid = tid >> 6, lane = tid & 63, q = lane >> 4, n = lane & 15;

  // ---- phase 0: issue x loads, zero inT + tile1, then scatter x -> tile1
  const float* xb = x + b * 3072;
  f32x4 xf[3];
#pragma unroll
  for (int k = 0; k < 3; ++k) xf[k] = ((const f32x4*)xb)[tid + 256 * k];
  for (int i = tid; i < 6480; i += 256) ((int*)inT)[i] = 0;
  for (int i = tid; i < 2312; i += 256) ((int*)tile1)[i] = 0;
  __syncthreads();
#pragma unroll
  for (int k = 0; k < 3; ++k) {
    int e0 = (tid + 256 * k) * 4;
#pragma unroll
    for (int jj = 0; jj < 4; ++jj) {
      int e = e0 + jj;
      int c = e >> 10, rem = e & 1023, iy = rem >> 5, ix = rem & 31;
      tile1[((iy + 1) * 34 + (ix + 1)) * 4 + c] = f2bf(xf[k][jj]);
    }
  }
  __syncthreads();

  // ---- phase 1: conv1 via MFMA + BN(folded) + ReLU + maxpool2 -> inT interior
  {
    const short8* wv1 = (const short8*)wp1;
    float sh1[2][4];
#pragma unroll
    for (int ct = 0; ct < 2; ++ct)
#pragma unroll
      for (int r = 0; r < 4; ++r) sh1[ct][r] = scsh[384 + ct * 16 + q * 4 + r];

    const s16x4 z4 = (s16x4)0;
#pragma unroll
    for (int h = 0; h < 2; ++h) {
      f32x4 acc[2][8]; // [ct][yy], y = 8*wid + yy, x = h*16 + n
#pragma unroll
      for (int ct = 0; ct < 2; ++ct)
#pragma unroll
        for (int yy = 0; yy < 8; ++yy) acc[ct][yy] = (f32x4)0.f;

#pragma unroll
      for (int off = 0; off < 9; ++off) {
        const int kyy = off / 3, kxx = off % 3;
        short8 a0 = wv1[(off * 2 + 0) * 64 + lane];
        short8 a1 = wv1[(off * 2 + 1) * 64 + lane];
#pragma unroll
        for (int yy = 0; yy < 8; ++yy) {
          int row = 8 * wid + yy + kyy;
          s16x4 blo = *(const s16x4*)&tile1[(row * 34 + h * 16 + kxx + n) * 4];
          short8 bfr = __builtin_shufflevector(blo, z4, 0, 1, 2, 3, 4, 5, 6, 7);
          acc[0][yy] =
              __builtin_amdgcn_mfma_f32_16x16x32_bf16(a0, bfr, acc[0][yy], 0, 0, 0);
          acc[1][yy] =
              __builtin_amdgcn_mfma_f32_16x16x32_bf16(a1, bfr, acc[1][yy], 0, 0, 0);
        }
      }
      // epilogue: shift + ReLU + 2x2 maxpool -> inT
#pragma unroll
      for (int ct = 0; ct < 2; ++ct)
#pragma unroll
        for (int yp = 0; yp < 4; ++yp)
#pragma unroll
          for (int r = 0; r < 4; ++r) {
            float v0 = fmaxf(acc[ct][2 * yp][r] + sh1[ct][r], 0.f);
            float v1 = fmaxf(acc[ct][2 * yp + 1][r] + sh1[ct][r], 0.f);
            float m = fmaxf(v0, v1);
            m = fmaxf(m, __shfl_xor(m, 1));
            if ((n & 1) == 0) {
              int co = ct * 16 + q * 4 + r;
              int yq = 4 * wid + yp, xq = 8 * h + (n >> 1);
              inT[((yq + 1) * 18 + (xq + 1)) * 40 + co] = f2bf(m);
            }
          }
    }
  }
  __syncthreads();

  // ---- phase 2: zero inT3 (tile1 is dead now)
  for (int i = tid; i < 3600; i += 256) ((int*)inT3)[i] = 0;
  __syncthreads();

  // ---- phase 3: conv2 MFMA + BN + ReLU + maxpool2 -> inT3 interior (bf16)
  {
    const short8* wv = (const short8*)wp2;
    f32x4 acc[4][4]; // [t][ct]
#pragma unroll
    for (int t = 0; t < 4; ++t)
#pragma unroll
      for (int ct = 0; ct < 4; ++ct) acc[t][ct] = (f32x4)0.f;

#pragma unroll
    for (int off = 0; off < 9; ++off) {
      const int ky = off / 3, kx = off % 3;
      short8 a[4];
#pragma unroll
      for (int ct = 0; ct < 4; ++ct) a[ct] = wv[(off * 4 + ct) * 64 + lane];
#pragma unroll
      for (int t = 0; t < 4; ++t) {
        int y = 4 * wid + t;
        short8 bf = *(const short8*)&inT[((y + ky) * 18 + (n + kx)) * 40 + q * 8];
#pragma unroll
        for (int ct = 0; ct < 4; ++ct)
          acc[t][ct] = __builtin_amdgcn_mfma_f32_16x16x32_bf16(a[ct], bf,
                                                               acc[t][ct], 0, 0, 0);
      }
    }

    const float* sc2 = scsh;
    const float* sh2 = scsh + 64;
#pragma unroll
    for (int ct = 0; ct < 4; ++ct) {
      float vm[4][4];
#pragma unroll
      for (int t = 0; t < 4; ++t)
#pragma unroll
        for (int r = 0; r < 4; ++r) {
          int co = ct * 16 + q * 4 + r;
          float v = fmaf(sc2[co], acc[t][ct][r], sh2[co]);
          v = fmaxf(v, 0.f);
          vm[t][r] = fmaxf(v, __shfl_xor(v, 1));
        }
#pragma unroll
      for (int pp = 0; pp < 2; ++pp)
#pragma unroll
        for (int r = 0; r < 4; ++r) {
          float m = fmaxf(vm[2 * pp][r], vm[2 * pp + 1][r]);
          if ((n & 1) == 0) {
            int co = ct * 16 + q * 4 + r;
            int y2 = 2 * wid + pp, x2 = n >> 1;
            inT3[((y2 + 1) * 10 + (x2 + 1)) * 72 + co] = f2bf(m);
          }
        }
    }
  }
  __syncthreads();

  // ---- phase 4: conv3 MFMA + BN + ReLU + avgpool2 -> out3 [B,2048]
  {
    const short8* wv = (const short8*)wp3;
    f32x4 acc[4][2]; // [c][tt]
#pragma unroll
    for (int c = 0; c < 4; ++c)
#pragma unroll
      for (int tt = 0; tt < 2; ++tt) acc[c][tt] = (f32x4)0.f;

    const int ct0 = (wid >> 1) * 4;
    const int t0 = (wid & 1) * 2;
#pragma unroll
    for (int off = 0; off < 9; ++off) {
      const int ky = off / 3, kx = off % 3;
#pragma unroll
      for (int half = 0; half < 2; ++half) {
        short8 a[4];
#pragma unroll
        for (int c = 0; c < 4; ++c)
          a[c] = wv[((off * 2 + half) * 8 + ct0 + c) * 64 + lane];
#pragma unroll
        for (int tt = 0; tt < 2; ++tt) {
          int y = 2 * (t0 + tt) + (n >> 3), xx = n & 7;
          short8 bf = *(const short8*)&inT3[((y + ky) * 10 + (xx + kx)) * 72 +
                                            half * 32 + q * 8];
#pragma unroll
          for (int c = 0; c < 4; ++c)
            acc[c][tt] = __builtin_amdgcn_mfma_f32_16x16x32_bf16(a[c], bf,
                                                                 acc[c][tt], 0, 0, 0);
        }
      }
    }

    const float* sc3 = scsh + 128;
    const float* sh3 = scsh + 256;
#pragma unroll
    for (int c = 0; c < 4; ++c) {
      int ct = ct0 + c;
#pragma unroll
      for (int tt = 0; tt < 2; ++tt) {
        int t = t0 + tt;
#pragma unroll
        for (int r = 0; r < 4; ++r) {
          int co = ct * 16 + q * 4 + r;
          float v = fmaf(sc3[co], acc[c][tt][r], sh3[co]);
          v = fmaxf(v, 0.f);
          float s = v + __shfl_xor(v, 1);
          s += __shfl_xor(s, 8);
          if ((n & 9) == 0)
            out3[(size_t)b * 2048 + co * 16 + t * 4 + (n >> 1)] = f2bf(s * 0.25f);
        }
      }
    }
  }
}

// ---------------- fr1 (MFMA): [1024,2048]bf16 x [512,2048]bf16^T +bias,ReLU ->
// f32 [1024,512]. 32x32 tile/block, grid 32x16=512 blocks, BK=64. -------------
__global__ __launch_bounds__(256) void k_fr1m(
    const short* __restrict__ A, const short* __restrict__ W,
    const float* __restrict__ bias, float* __restrict__ C) {
  __shared__ __align__(16) short As[32 * 72];
  __shared__ __align__(16) short Bs[32 * 72];
  const int m0 = blockIdx.x * 32;
  const int n0 = blockIdx.y * 32;
  const int tid = threadIdx.x;
  const int w = tid >> 6, lane = tid & 63, q = lane >> 4, n = lane & 15;
  const int mt = w >> 1, nt = w & 1;
  const int srow = tid >> 3, sc = tid & 7;

  f32x4 acc = (f32x4)0.f;
  const short* Ab = A + (size_t)(m0 + srow) * 2048 + sc * 8;
  const short* Wb = W + (size_t)(n0 + srow) * 2048 + sc * 8;

  for (int k0 = 0; k0 < 2048; k0 += 64) {
    short8 av = *(const short8*)(Ab + k0);
    short8 bv = *(const short8*)(Wb + k0);
    __syncthreads();
    *(short8*)&As[srow * 72 + sc * 8] = av;
    *(short8*)&Bs[srow * 72 + sc * 8] = bv;
    __syncthreads();
#pragma unroll
    for (int kk = 0; kk < 2; ++kk) {
      short8 bfrag = *(const short8*)&Bs[(nt * 16 + n) * 72 + kk * 32 + q * 8];
      short8 afrag = *(const short8*)&As[(mt * 16 + n) * 72 + kk * 32 + q * 8];
      acc = __builtin_amdgcn_mfma_f32_16x16x32_bf16(afrag, bfrag, acc, 0, 0, 0);
    }
  }
#pragma unroll
  for (int r = 0; r < 4; ++r) {
    int m = m0 + mt * 16 + q * 4 + r;
    int nn = n0 + nt * 16 + n;
    C[(size_t)m * 512 + nn] = fmaxf(acc[r] + bias[nn], 0.f);
  }
}

// ---------------- tail: fr2 + softmax + quantum + head ----------------------
__global__ __launch_bounds__(64) void k_tail(
    const float* __restrict__ H, const float* __restrict__ W2,
    const float* __restrict__ b2, const float* __restrict__ qw,
    const float* __restrict__ h1w, const float* __restrict__ h1b,
    const float* __restrict__ bg, const float* __restrict__ bb,
    const float* __restrict__ h2w, const float* __restrict__ h2b,
    float* __restrict__ out) {
  __shared__ float hbuf[512];
  __shared__ float ybuf[128];
  const int b = blockIdx.x;
  const int lane = threadIdx.x;
  const float* hrow = H + b * 512;
  *(float4*)&hbuf[lane * 4] = *(const float4*)&hrow[lane * 4];
  *(float4*)&hbuf[256 + lane * 4] = *(const float4*)&hrow[256 + lane * 4];
  __syncthreads();

  const int j = lane & 15;
  const int grpk = lane >> 4;
  float partial = 0.f;
  const float* wrow = W2 + j * 512 + grpk * 128;
  const float* hb = hbuf + grpk * 128;
#pragma unroll
  for (int k = 0; k < 128; k += 4) {
    float4 wv = *(const float4*)&wrow[k];
    partial = fmaf(wv.x, hb[k + 0], partial);
    partial = fmaf(wv.y, hb[k + 1], partial);
    partial = fmaf(wv.z, hb[k + 2], partial);
    partial = fmaf(wv.w, hb[k + 3], partial);
  }
  partial += __shfl_xor(partial, 16);
  partial += __shfl_xor(partial, 32);
  float logit = partial + b2[j];

  float m = logit;
#pragma unroll
  for (int d = 1; d < 16; d <<= 1) m = fmaxf(m, __shfl_xor(m, d));
  float e = expf(logit - m);
  float s = e;
#pragma unroll
  for (int d = 1; d < 16; d <<= 1) s += __shfl_xor(s, d);
  float p = e / s;

  float n2 = p * p;
#pragma unroll
  for (int d = 1; d < 16; d <<= 1) n2 += __shfl_xor(n2, d);
  float amp = p / sqrtf(n2);
  float re = amp, im = 0.f;

#pragma unroll
  for (int l = 0; l < 2; ++l) {
#pragma unroll
    for (int q = 0; q < 4; ++q) {
      float th = qw[l * 4 + q] * 0.5f;
      float c = cosf(th), sn = sinf(th);
      int mask = 1 << (3 - q);
      float pre = __shfl_xor(re, mask);
      float pim = __shfl_xor(im, mask);
      float nre = fmaf(c, re, sn * pim);
      float nim = fmaf(c, im, -sn * pre);
      re = nre;
      im = nim;
    }
    int src = j;
    if (src & 1) src ^= 8;
    if (src & 2) src ^= 1;
    if (src & 4) src ^= 2;
    if (src & 8) src ^= 4;
    int srclane = (lane & 48) | src;
    re = __shfl(re, srclane);
    im = __shfl(im, srclane);
  }

  float prob = re * re + im * im;
  float qv[4];
#pragma unroll
  for (int w = 0; w < 4; ++w) {
    float sgn = ((j >> (3 - w)) & 1) ? -1.f : 1.f;
    float cwv = prob * sgn;
    cwv += __shfl_xor(cwv, 1);
    cwv += __shfl_xor(cwv, 2);
    cwv += __shfl_xor(cwv, 4);
    cwv += __shfl_xor(cwv, 8);
    qv[w] = cwv;
  }

#pragma unroll
  for (int t = 0; t < 2; ++t) {
    int jj = lane + 64 * t;
    float4 hw = *(const float4*)&h1w[jj * 4];
    float y = h1b[jj];
    y = fmaf(hw.x, qv[0], y);
    y = fmaf(hw.y, qv[1], y);
    y = fmaf(hw.z, qv[2], y);
    y = fmaf(hw.w, qv[3], y);
    y = fmaf(bg[jj] * BN_INV, y, bb[jj]);
    ybuf[jj] = fmaxf(y, 0.f);
  }
  __syncthreads();

#pragma unroll
  for (int t = 0; t < 2; ++t) {
    int k = lane + 64 * t;
    if (k < 100) {
      const float* wr = h2w + k * 128;
      float o = h2b[k];
#pragma unroll
      for (int jj = 0; jj < 128; jj += 4) {
        float4 wv = *(const float4*)&wr[jj];
        o = fmaf(wv.x, ybuf[jj + 0], o);
        o = fmaf(wv.y, ybuf[jj + 1], o);
        o = fmaf(wv.z, ybuf[jj + 2], o);
        o = fmaf(wv.w, ybuf[jj + 3], o);
      }
      out[b * 100 + k] = o;
    }
  }
}

extern "C" void kernel_launch(void* const* d_in, const int* in_sizes, int n_in,
                              void* d_out, int out_size, void* d_ws,
                              size_t ws_size, hipStream_t stream) {
  const float* x = (const float*)d_in[0];
  const float* c1w = (const float*)d_in[1];
  const float* c1b = (const float*)d_in[2];
  const float* g1 = (const float*)d_in[3];
  const float* be1 = (const float*)d_in[4];
  const float* c2w = (const float*)d_in[5];
  const float* c2b = (const float*)d_in[6];
  const float* g2 = (const float*)d_in[7];
  const float* be2 = (const float*)d_in[8];
  const float* c3w = (const float*)d_in[9];
  const float* c3b = (const float*)d_in[10];
  const float* g3 = (const float*)d_in[11];
  const float* be3 = (const float*)d_in[12];
  const float* fr1w = (const float*)d_in[13];
  const float* fr1b = (const float*)d_in[14];
  const float* fr2w = (const float*)d_in[15];
  const float* fr2b = (const float*)d_in[16];
  const float* qwts = (const float*)d_in[17];
  const float* h1w = (const float*)d_in[18];
  const float* h1b = (const float*)d_in[19];
  const float* bhg = (const float*)d_in[20];
  const float* bhb = (const float*)d_in[21];
  const float* h2w = (const float*)d_in[22];
  const float* h2b = (const float*)d_in[23];
  float* out = (float*)d_out;

  float* ws = (float*)d_ws;
  // layout (float offsets), total ~8.6 MB:
  //   out3bf [0, 1048576)          bf16 [1024,2048]
  //   h1     [1048576, 1572864)    f32  [1024,512]
  //   wfr1   [1572864, 2097152)    bf16 [512,2048]
  //   wp2    [2097152, +9216)      bf16 18432
  //   wp3    [2106368, +36864)     bf16 73728
  //   scsh   [2143232, +512)       f32 416 used
  //   wp1    [2143744, +4608)      bf16 9216
  short* out3bf = (short*)ws;
  float* h1 = ws + 1048576;
  short* wfr1 = (short*)(ws + 1572864);
  short* wp2 = (short*)(ws + 2097152);
  short* wp3 = (short*)(ws + 2106368);
  float* scsh = ws + 2143232;
  short* wp1 = (short*)(ws + 2143744);

  k_prepack<<<96, 256, 0, stream>>>(c1w, c1b, g1, be1, c2w, c2b, g2, be2, c3w,
                                    c3b, g3, be3, wp1, wp2, wp3, scsh);
  k_convfused<<<NB + 128, 256, 0, stream>>>(x, wp1, wp2, wp3, scsh, fr1w, wfr1,
                                            out3bf);
  k_fr1m<<<dim3(32, 16), 256, 0, stream>>>(out3bf, wfr1, fr1b, h1);
  k_tail<<<NB, 64, 0, stream>>>(h1, fr2w, fr2b, qwts, h1w, h1b, bhg, bhb, h2w,
                                h2b, out);
}

// Round 4
// 186.233 us; speedup vs baseline: 1.6321x; 1.6321x over previous
//
#include <hip/hip_runtime.h>
#include <math.h>

#define NB 1024
static constexpr float BN_INV = 0.99999500003749975f; // 1/sqrt(1+1e-5)

typedef __attribute__((ext_vector_type(8))) short short8;
typedef __attribute__((ext_vector_type(4))) short s16x4;
typedef __attribute__((ext_vector_type(4))) float f32x4;

__device__ inline short f2bf(float f) {
  union { float f; unsigned u; } v;
  v.f = f;
  unsigned u = v.u;
  u += 0x7fff + ((u >> 16) & 1); // RNE
  return (short)(u >> 16);
}

// ---------------- prepack: conv1/conv2/conv3 weights -> MFMA A-frag bf16,
// BN folded. conv1: scale folded into weights, shift into scsh[384..416).
__global__ void k_prepack(const float* __restrict__ c1w, const float* __restrict__ c1b,
                          const float* __restrict__ g1, const float* __restrict__ be1,
                          const float* __restrict__ c2w, const float* __restrict__ c2b,
                          const float* __restrict__ g2, const float* __restrict__ be2,
                          const float* __restrict__ c3w, const float* __restrict__ c3b,
                          const float* __restrict__ g3, const float* __restrict__ be3,
                          short* __restrict__ wp1, short* __restrict__ wp2,
                          short* __restrict__ wp3, float* __restrict__ scsh) {
  int i = blockIdx.x * 256 + threadIdx.x;
  int stride = gridDim.x * 256;
  // conv1: A[co][k] = w1[co][c=k][ky][kx] * g1[co] * BN_INV for k<3 else 0
  for (int e = i; e < 9216; e += stride) {
    int j = e & 7, lane = (e >> 3) & 63, ct = (e >> 9) & 1, off = e >> 10;
    int co = ct * 16 + (lane & 15), k = (lane >> 4) * 8 + j;
    float v = 0.f;
    if (k < 3) v = c1w[(co * 3 + k) * 9 + off] * g1[co] * BN_INV;
    wp1[e] = f2bf(v);
  }
  for (int e = i; e < 18432; e += stride) {
    int j = e & 7, lane = (e >> 3) & 63, ct = (e >> 9) & 3, off = e >> 11;
    int co = ct * 16 + (lane & 15), ci = (lane >> 4) * 8 + j;
    wp2[e] = f2bf(c2w[(co * 32 + ci) * 9 + off]);
  }
  for (int e = i; e < 73728; e += stride) {
    int j = e & 7, lane = (e >> 3) & 63, ct = (e >> 9) & 7, oh = e >> 12;
    int half = oh & 1, off = oh >> 1;
    int co = ct * 16 + (lane & 15), ci = half * 32 + (lane >> 4) * 8 + j;
    wp3[e] = f2bf(c3w[(co * 64 + ci) * 9 + off]);
  }
  if (i < 64) {
    float sc = g2[i] * BN_INV;
    scsh[i] = sc;
    scsh[64 + i] = sc * c2b[i] + be2[i];
  } else if (i < 192) {
    int c = i - 64;
    float sc = g3[c] * BN_INV;
    scsh[128 + c] = sc;
    scsh[256 + c] = sc * c3b[c] + be3[c];
  } else if (i < 224) {
    int c = i - 192;
    scsh[384 + c] = g1[c] * BN_INV * c1b[c] + be1[c];
  }
}

// ---------------- fused conv1+conv2+conv3 (per-batch-image block) -----------
// Blocks [0,1024): conv pipeline, all intermediates in LDS. conv1 via MFMA
// (3 input channels on K, zero-padded to 4; A zero-padded k>=4).
// Blocks [1024,1152): fr1_w f32 -> bf16 conversion (independent side work).
// LDS: inT [18*18][40] bf16 (25920 B) | union{ tile1 [34*34][4] bf16 (9248 B),
//                                              inT3 [10*10][72] bf16 (14400 B)}
// total 40320 B -> 4 blocks/CU. NOTE: no min-waves launch bound — round-3's
// (256,4) made the compiler pick 64 VGPR and spill ~540 MB of scratch.
// conv1 acc restructured to 8 live f32x4 (ct outer loop) as spill insurance.
__global__ __launch_bounds__(256) void k_convfused(
    const float* __restrict__ x, const short* __restrict__ wp1,
    const short* __restrict__ wp2, const short* __restrict__ wp3,
    const float* __restrict__ scsh, const float* __restrict__ fr1w,
    short* __restrict__ wfr1, short* __restrict__ out3 /* bf16 [B,2048] */) {
  __shared__ __align__(16) char smem[40320];
  const int tid = threadIdx.x;
  const int bx = blockIdx.x;

  if (bx >= NB) {
    // fr1_w: 512*2048 f32 -> bf16, two at a time, 128 blocks
    int i = (bx - NB) * 256 + tid;
    for (int e = i; e < 524288; e += 128 * 256) {
      float2 f = ((const float2*)fr1w)[e];
      unsigned lo = (unsigned)(unsigned short)f2bf(f.x);
      unsigned hi = (unsigned)(unsigned short)f2bf(f.y);
      ((unsigned*)wfr1)[e] = (hi << 16) | lo;
    }
    return;
  }

  short* inT = (short*)smem;             // conv1 out, padded, ch-padded to 40
  short* tile1 = (short*)(smem + 25920); // conv1 input bf16 [34][34][4]
  short* inT3 = (short*)(smem + 25920);  // conv2 out (phase 2+), aliases tile1

  const int b = bx;
  const int wid = tid >> 6, lane = tid & 63, q = lane >> 4, n = lane & 15;

  // ---- phase 0: issue x loads, zero inT + tile1, then scatter x -> tile1
  const float* xb = x + b * 3072;
  f32x4 xf[3];
#pragma unroll
  for (int k = 0; k < 3; ++k) xf[k] = ((const f32x4*)xb)[tid + 256 * k];
  for (int i = tid; i < 6480; i += 256) ((int*)inT)[i] = 0;
  for (int i = tid; i < 2312; i += 256) ((int*)tile1)[i] = 0;
  __syncthreads();
#pragma unroll
  for (int k = 0; k < 3; ++k) {
    int e0 = (tid + 256 * k) * 4;
#pragma unroll
    for (int jj = 0; jj < 4; ++jj) {
      int e = e0 + jj;
      int c = e >> 10, rem = e & 1023, iy = rem >> 5, ix = rem & 31;
      tile1[((iy + 1) * 34 + (ix + 1)) * 4 + c] = f2bf(xf[k][jj]);
    }
  }
  __syncthreads();

  // ---- phase 1: conv1 via MFMA + BN(folded) + ReLU + maxpool2 -> inT interior
  {
    const short8* wv1 = (const short8*)wp1;
    const s16x4 z4 = (s16x4)0;
#pragma unroll
    for (int h = 0; h < 2; ++h) {
#pragma unroll
      for (int ct = 0; ct < 2; ++ct) {
        f32x4 acc[8]; // y = 8*wid + yy, x = h*16 + n, co = ct*16 + (C/D row)
#pragma unroll
        for (int yy = 0; yy < 8; ++yy) acc[yy] = (f32x4)0.f;
#pragma unroll
        for (int off = 0; off < 9; ++off) {
          const int kyy = off / 3, kxx = off % 3;
          short8 a = wv1[(off * 2 + ct) * 64 + lane];
#pragma unroll
          for (int yy = 0; yy < 8; ++yy) {
            int row = 8 * wid + yy + kyy;
            s16x4 blo = *(const s16x4*)&tile1[(row * 34 + h * 16 + kxx + n) * 4];
            short8 bfr = __builtin_shufflevector(blo, z4, 0, 1, 2, 3, 4, 5, 6, 7);
            acc[yy] =
                __builtin_amdgcn_mfma_f32_16x16x32_bf16(a, bfr, acc[yy], 0, 0, 0);
          }
        }
        // epilogue for this co-tile: shift + ReLU + 2x2 maxpool -> inT
        float sh1r[4];
#pragma unroll
        for (int r = 0; r < 4; ++r) sh1r[r] = scsh[384 + ct * 16 + q * 4 + r];
#pragma unroll
        for (int yp = 0; yp < 4; ++yp)
#pragma unroll
          for (int r = 0; r < 4; ++r) {
            float v0 = fmaxf(acc[2 * yp][r] + sh1r[r], 0.f);
            float v1 = fmaxf(acc[2 * yp + 1][r] + sh1r[r], 0.f);
            float m = fmaxf(v0, v1);
            m = fmaxf(m, __shfl_xor(m, 1));
            if ((n & 1) == 0) {
              int co = ct * 16 + q * 4 + r;
              int yq = 4 * wid + yp, xq = 8 * h + (n >> 1);
              inT[((yq + 1) * 18 + (xq + 1)) * 40 + co] = f2bf(m);
            }
          }
      }
    }
  }
  __syncthreads();

  // ---- phase 2: zero inT3 (tile1 is dead now)
  for (int i = tid; i < 3600; i += 256) ((int*)inT3)[i] = 0;
  __syncthreads();

  // ---- phase 3: conv2 MFMA + BN + ReLU + maxpool2 -> inT3 interior (bf16)
  {
    const short8* wv = (const short8*)wp2;
    f32x4 acc[4][4]; // [t][ct]
#pragma unroll
    for (int t = 0; t < 4; ++t)
#pragma unroll
      for (int ct = 0; ct < 4; ++ct) acc[t][ct] = (f32x4)0.f;

#pragma unroll
    for (int off = 0; off < 9; ++off) {
      const int ky = off / 3, kx = off % 3;
      short8 a[4];
#pragma unroll
      for (int ct = 0; ct < 4; ++ct) a[ct] = wv[(off * 4 + ct) * 64 + lane];
#pragma unroll
      for (int t = 0; t < 4; ++t) {
        int y = 4 * wid + t;
        short8 bf = *(const short8*)&inT[((y + ky) * 18 + (n + kx)) * 40 + q * 8];
#pragma unroll
        for (int ct = 0; ct < 4; ++ct)
          acc[t][ct] = __builtin_amdgcn_mfma_f32_16x16x32_bf16(a[ct], bf,
                                                               acc[t][ct], 0, 0, 0);
      }
    }

    const float* sc2 = scsh;
    const float* sh2 = scsh + 64;
#pragma unroll
    for (int ct = 0; ct < 4; ++ct) {
      float vm[4][4];
#pragma unroll
      for (int t = 0; t < 4; ++t)
#pragma unroll
        for (int r = 0; r < 4; ++r) {
          int co = ct * 16 + q * 4 + r;
          float v = fmaf(sc2[co], acc[t][ct][r], sh2[co]);
          v = fmaxf(v, 0.f);
          vm[t][r] = fmaxf(v, __shfl_xor(v, 1));
        }
#pragma unroll
      for (int pp = 0; pp < 2; ++pp)
#pragma unroll
        for (int r = 0; r < 4; ++r) {
          float m = fmaxf(vm[2 * pp][r], vm[2 * pp + 1][r]);
          if ((n & 1) == 0) {
            int co = ct * 16 + q * 4 + r;
            int y2 = 2 * wid + pp, x2 = n >> 1;
            inT3[((y2 + 1) * 10 + (x2 + 1)) * 72 + co] = f2bf(m);
          }
        }
    }
  }
  __syncthreads();

  // ---- phase 4: conv3 MFMA + BN + ReLU + avgpool2 -> out3 [B,2048]
  {
    const short8* wv = (const short8*)wp3;
    f32x4 acc[4][2]; // [c][tt]
#pragma unroll
    for (int c = 0; c < 4; ++c)
#pragma unroll
      for (int tt = 0; tt < 2; ++tt) acc[c][tt] = (f32x4)0.f;

    const int ct0 = (wid >> 1) * 4;
    const int t0 = (wid & 1) * 2;
#pragma unroll
    for (int off = 0; off < 9; ++off) {
      const int ky = off / 3, kx = off % 3;
#pragma unroll
      for (int half = 0; half < 2; ++half) {
        short8 a[4];
#pragma unroll
        for (int c = 0; c < 4; ++c)
          a[c] = wv[((off * 2 + half) * 8 + ct0 + c) * 64 + lane];
#pragma unroll
        for (int tt = 0; tt < 2; ++tt) {
          int y = 2 * (t0 + tt) + (n >> 3), xx = n & 7;
          short8 bf = *(const short8*)&inT3[((y + ky) * 10 + (xx + kx)) * 72 +
                                            half * 32 + q * 8];
#pragma unroll
          for (int c = 0; c < 4; ++c)
            acc[c][tt] = __builtin_amdgcn_mfma_f32_16x16x32_bf16(a[c], bf,
                                                                 acc[c][tt], 0, 0, 0);
        }
      }
    }

    const float* sc3 = scsh + 128;
    const float* sh3 = scsh + 256;
#pragma unroll
    for (int c = 0; c < 4; ++c) {
      int ct = ct0 + c;
#pragma unroll
      for (int tt = 0; tt < 2; ++tt) {
        int t = t0 + tt;
#pragma unroll
        for (int r = 0; r < 4; ++r) {
          int co = ct * 16 + q * 4 + r;
          float v = fmaf(sc3[co], acc[c][tt][r], sh3[co]);
          v = fmaxf(v, 0.f);
          float s = v + __shfl_xor(v, 1);
          s += __shfl_xor(s, 8);
          if ((n & 9) == 0)
            out3[(size_t)b * 2048 + co * 16 + t * 4 + (n >> 1)] = f2bf(s * 0.25f);
        }
      }
    }
  }
}

// ---------------- fr1 (MFMA): [1024,2048]bf16 x [512,2048]bf16^T +bias,ReLU ->
// f32 [1024,512]. 32x32 tile/block, grid 32x16=512 blocks, BK=64. -------------
__global__ __launch_bounds__(256) void k_fr1m(
    const short* __restrict__ A, const short* __restrict__ W,
    const float* __restrict__ bias, float* __restrict__ C) {
  __shared__ __align__(16) short As[32 * 72];
  __shared__ __align__(16) short Bs[32 * 72];
  const int m0 = blockIdx.x * 32;
  const int n0 = blockIdx.y * 32;
  const int tid = threadIdx.x;
  const int w = tid >> 6, lane = tid & 63, q = lane >> 4, n = lane & 15;
  const int mt = w >> 1, nt = w & 1;
  const int srow = tid >> 3, sc = tid & 7;

  f32x4 acc = (f32x4)0.f;
  const short* Ab = A + (size_t)(m0 + srow) * 2048 + sc * 8;
  const short* Wb = W + (size_t)(n0 + srow) * 2048 + sc * 8;

  for (int k0 = 0; k0 < 2048; k0 += 64) {
    short8 av = *(const short8*)(Ab + k0);
    short8 bv = *(const short8*)(Wb + k0);
    __syncthreads();
    *(short8*)&As[srow * 72 + sc * 8] = av;
    *(short8*)&Bs[srow * 72 + sc * 8] = bv;
    __syncthreads();
#pragma unroll
    for (int kk = 0; kk < 2; ++kk) {
      short8 bfrag = *(const short8*)&Bs[(nt * 16 + n) * 72 + kk * 32 + q * 8];
      short8 afrag = *(const short8*)&As[(mt * 16 + n) * 72 + kk * 32 + q * 8];
      acc = __builtin_amdgcn_mfma_f32_16x16x32_bf16(afrag, bfrag, acc, 0, 0, 0);
    }
  }
#pragma unroll
  for (int r = 0; r < 4; ++r) {
    int m = m0 + mt * 16 + q * 4 + r;
    int nn = n0 + nt * 16 + n;
    C[(size_t)m * 512 + nn] = fmaxf(acc[r] + bias[nn], 0.f);
  }
}

// ---------------- tail: fr2 + softmax + quantum + head ----------------------
__global__ __launch_bounds__(64) void k_tail(
    const float* __restrict__ H, const float* __restrict__ W2,
    const float* __restrict__ b2, const float* __restrict__ qw,
    const float* __restrict__ h1w, const float* __restrict__ h1b,
    const float* __restrict__ bg, const float* __restrict__ bb,
    const float* __restrict__ h2w, const float* __restrict__ h2b,
    float* __restrict__ out) {
  __shared__ float hbuf[512];
  __shared__ float ybuf[128];
  const int b = blockIdx.x;
  const int lane = threadIdx.x;
  const float* hrow = H + b * 512;
  *(float4*)&hbuf[lane * 4] = *(const float4*)&hrow[lane * 4];
  *(float4*)&hbuf[256 + lane * 4] = *(const float4*)&hrow[256 + lane * 4];
  __syncthreads();

  const int j = lane & 15;
  const int grpk = lane >> 4;
  float partial = 0.f;
  const float* wrow = W2 + j * 512 + grpk * 128;
  const float* hb = hbuf + grpk * 128;
#pragma unroll
  for (int k = 0; k < 128; k += 4) {
    float4 wv = *(const float4*)&wrow[k];
    partial = fmaf(wv.x, hb[k + 0], partial);
    partial = fmaf(wv.y, hb[k + 1], partial);
    partial = fmaf(wv.z, hb[k + 2], partial);
    partial = fmaf(wv.w, hb[k + 3], partial);
  }
  partial += __shfl_xor(partial, 16);
  partial += __shfl_xor(partial, 32);
  float logit = partial + b2[j];

  float m = logit;
#pragma unroll
  for (int d = 1; d < 16; d <<= 1) m = fmaxf(m, __shfl_xor(m, d));
  float e = expf(logit - m);
  float s = e;
#pragma unroll
  for (int d = 1; d < 16; d <<= 1) s += __shfl_xor(s, d);
  float p = e / s;

  float n2 = p * p;
#pragma unroll
  for (int d = 1; d < 16; d <<= 1) n2 += __shfl_xor(n2, d);
  float amp = p / sqrtf(n2);
  float re = amp, im = 0.f;

#pragma unroll
  for (int l = 0; l < 2; ++l) {
#pragma unroll
    for (int q = 0; q < 4; ++q) {
      float th = qw[l * 4 + q] * 0.5f;
      float c = cosf(th), sn = sinf(th);
      int mask = 1 << (3 - q);
      float pre = __shfl_xor(re, mask);
      float pim = __shfl_xor(im, mask);
      float nre = fmaf(c, re, sn * pim);
      float nim = fmaf(c, im, -sn * pre);
      re = nre;
      im = nim;
    }
    int src = j;
    if (src & 1) src ^= 8;
    if (src & 2) src ^= 1;
    if (src & 4) src ^= 2;
    if (src & 8) src ^= 4;
    int srclane = (lane & 48) | src;
    re = __shfl(re, srclane);
    im = __shfl(im, srclane);
  }

  float prob = re * re + im * im;
  float qv[4];
#pragma unroll
  for (int w = 0; w < 4; ++w) {
    float sgn = ((j >> (3 - w)) & 1) ? -1.f : 1.f;
    float cwv = prob * sgn;
    cwv += __shfl_xor(cwv, 1);
    cwv += __shfl_xor(cwv, 2);
    cwv += __shfl_xor(cwv, 4);
    cwv += __shfl_xor(cwv, 8);
    qv[w] = cwv;
  }

#pragma unroll
  for (int t = 0; t < 2; ++t) {
    int jj = lane + 64 * t;
    float4 hw = *(const float4*)&h1w[jj * 4];
    float y = h1b[jj];
    y = fmaf(hw.x, qv[0], y);
    y = fmaf(hw.y, qv[1], y);
    y = fmaf(hw.z, qv[2], y);
    y = fmaf(hw.w, qv[3], y);
    y = fmaf(bg[jj] * BN_INV, y, bb[jj]);
    ybuf[jj] = fmaxf(y, 0.f);
  }
  __syncthreads();

#pragma unroll
  for (int t = 0; t < 2; ++t) {
    int k = lane + 64 * t;
    if (k < 100) {
      const float* wr = h2w + k * 128;
      float o = h2b[k];
#pragma unroll
      for (int jj = 0; jj < 128; jj += 4) {
        float4 wv = *(const float4*)&wr[jj];
        o = fmaf(wv.x, ybuf[jj + 0], o);
        o = fmaf(wv.y, ybuf[jj + 1], o);
        o = fmaf(wv.z, ybuf[jj + 2], o);
        o = fmaf(wv.w, ybuf[jj + 3], o);
      }
      out[b * 100 + k] = o;
    }
  }
}

extern "C" void kernel_launch(void* const* d_in, const int* in_sizes, int n_in,
                              void* d_out, int out_size, void* d_ws,
                              size_t ws_size, hipStream_t stream) {
  const float* x = (const float*)d_in[0];
  const float* c1w = (const float*)d_in[1];
  const float* c1b = (const float*)d_in[2];
  const float* g1 = (const float*)d_in[3];
  const float* be1 = (const float*)d_in[4];
  const float* c2w = (const float*)d_in[5];
  const float* c2b = (const float*)d_in[6];
  const float* g2 = (const float*)d_in[7];
  const float* be2 = (const float*)d_in[8];
  const float* c3w = (const float*)d_in[9];
  const float* c3b = (const float*)d_in[10];
  const float* g3 = (const float*)d_in[11];
  const float* be3 = (const float*)d_in[12];
  const float* fr1w = (const float*)d_in[13];
  const float* fr1b = (const float*)d_in[14];
  const float* fr2w = (const float*)d_in[15];
  const float* fr2b = (const float*)d_in[16];
  const float* qwts = (const float*)d_in[17];
  const float* h1w = (const float*)d_in[18];
  const float* h1b = (const float*)d_in[19];
  const float* bhg = (const float*)d_in[20];
  const float* bhb = (const float*)d_in[21];
  const float* h2w = (const float*)d_in[22];
  const float* h2b = (const float*)d_in[23];
  float* out = (float*)d_out;

  float* ws = (float*)d_ws;
  // layout (float offsets), total ~8.6 MB:
  //   out3bf [0, 1048576)          bf16 [1024,2048]
  //   h1     [1048576, 1572864)    f32  [1024,512]
  //   wfr1   [1572864, 2097152)    bf16 [512,2048]
  //   wp2    [2097152, +9216)      bf16 18432
  //   wp3    [2106368, +36864)     bf16 73728
  //   scsh   [2143232, +512)       f32 416 used
  //   wp1    [2143744, +4608)      bf16 9216
  short* out3bf = (short*)ws;
  float* h1 = ws + 1048576;
  short* wfr1 = (short*)(ws + 1572864);
  short* wp2 = (short*)(ws + 2097152);
  short* wp3 = (short*)(ws + 2106368);
  float* scsh = ws + 2143232;
  short* wp1 = (short*)(ws + 2143744);

  k_prepack<<<96, 256, 0, stream>>>(c1w, c1b, g1, be1, c2w, c2b, g2, be2, c3w,
                                    c3b, g3, be3, wp1, wp2, wp3, scsh);
  k_convfused<<<NB + 128, 256, 0, stream>>>(x, wp1, wp2, wp3, scsh, fr1w, wfr1,
                                            out3bf);
  k_fr1m<<<dim3(32, 16), 256, 0, stream>>>(out3bf, wfr1, fr1b, h1);
  k_tail<<<NB, 64, 0, stream>>>(h1, fr2w, fr2b, qwts, h1w, h1b, bhg, bhb, h2w,
                                h2b, out);
}

// Round 5
// 178.224 us; speedup vs baseline: 1.7055x; 1.0449x over previous
//
#include <hip/hip_runtime.h>
#include <math.h>

#define NB 1024
static constexpr float BN_INV = 0.99999500003749975f; // 1/sqrt(1+1e-5)

typedef __attribute__((ext_vector_type(8))) short short8;
typedef __attribute__((ext_vector_type(4))) short s16x4;
typedef __attribute__((ext_vector_type(4))) float f32x4;

__device__ inline short f2bf(float f) {
  union { float f; unsigned u; } v;
  v.f = f;
  unsigned u = v.u;
  u += 0x7fff + ((u >> 16) & 1); // RNE
  return (short)(u >> 16);
}

// ---------------- prepack: conv weights -> MFMA A-frag bf16, BN folded ------
// conv1 K-packed: mf0: k = ky*16 + kx*4 + c (ky 0..1, kx 0..3 pad, c 0..3 pad)
//                 mf1: k = kx*4 + c, ky=2 (k>=16 zero)
// scale folded into conv1 weights; shift into scsh[384..416).
__global__ void k_prepack(const float* __restrict__ c1w, const float* __restrict__ c1b,
                          const float* __restrict__ g1, const float* __restrict__ be1,
                          const float* __restrict__ c2w, const float* __restrict__ c2b,
                          const float* __restrict__ g2, const float* __restrict__ be2,
                          const float* __restrict__ c3w, const float* __restrict__ c3b,
                          const float* __restrict__ g3, const float* __restrict__ be3,
                          short* __restrict__ wp1, short* __restrict__ wp2,
                          short* __restrict__ wp3, float* __restrict__ scsh) {
  int i = blockIdx.x * 256 + threadIdx.x;
  int stride = gridDim.x * 256;
  // conv1 A-frags: 2 mf x 2 ct x 64 lanes x 8 = 2048 bf16
  for (int e = i; e < 2048; e += stride) {
    int j = e & 7, lane = (e >> 3) & 63, ct = (e >> 9) & 1, mf = e >> 10;
    int co = ct * 16 + (lane & 15), k = (lane >> 4) * 8 + j;
    int kx = (k >> 2) & 3, c = k & 3;
    float v = 0.f;
    if (mf == 0) {
      int ky = k >> 4;
      if (kx < 3 && c < 3) v = c1w[(co * 3 + c) * 9 + ky * 3 + kx] * g1[co] * BN_INV;
    } else {
      if (k < 16 && kx < 3 && c < 3)
        v = c1w[(co * 3 + c) * 9 + 6 + kx] * g1[co] * BN_INV;
    }
    wp1[e] = f2bf(v);
  }
  for (int e = i; e < 18432; e += stride) {
    int j = e & 7, lane = (e >> 3) & 63, ct = (e >> 9) & 3, off = e >> 11;
    int co = ct * 16 + (lane & 15), ci = (lane >> 4) * 8 + j;
    wp2[e] = f2bf(c2w[(co * 32 + ci) * 9 + off]);
  }
  for (int e = i; e < 73728; e += stride) {
    int j = e & 7, lane = (e >> 3) & 63, ct = (e >> 9) & 7, oh = e >> 12;
    int half = oh & 1, off = oh >> 1;
    int co = ct * 16 + (lane & 15), ci = half * 32 + (lane >> 4) * 8 + j;
    wp3[e] = f2bf(c3w[(co * 64 + ci) * 9 + off]);
  }
  if (i < 64) {
    float sc = g2[i] * BN_INV;
    scsh[i] = sc;
    scsh[64 + i] = sc * c2b[i] + be2[i];
  } else if (i < 192) {
    int c = i - 64;
    float sc = g3[c] * BN_INV;
    scsh[128 + c] = sc;
    scsh[256 + c] = sc * c3b[c] + be3[c];
  } else if (i < 224) {
    int c = i - 192;
    scsh[384 + c] = g1[c] * BN_INV * c1b[c] + be1[c];
  }
}

// ---------------- fused conv1+conv2+conv3 (per-batch-image block) -----------
// Blocks [0,128): fr1_w f32->bf16 conversion (dispatched FIRST so it overlaps).
// Blocks [128,128+1024): conv pipeline, all intermediates in LDS.
// conv1 via tap-packed MFMA (2 MFMAs per 16-pixel tile instead of 9x4-waste).
// LDS: inT [18*18][40] bf16 (25920 B) | union{ tile1 [34*34+4][4] bf16 (9280 B),
//                                              inT3 [10*10][72] bf16 (14400 B)}
__global__ __launch_bounds__(256) void k_convfused(
    const float* __restrict__ x, const short* __restrict__ wp1,
    const short* __restrict__ wp2, const short* __restrict__ wp3,
    const float* __restrict__ scsh, const float* __restrict__ fr1w,
    short* __restrict__ wfr1, short* __restrict__ out3 /* bf16 [B,2048] */) {
  __shared__ __align__(16) char smem[40320];
  const int tid = threadIdx.x;
  const int bx = blockIdx.x;

  if (bx < 128) {
    // fr1_w: 512*2048 f32 -> bf16, two at a time, 128 blocks
    int i = bx * 256 + tid;
    for (int e = i; e < 524288; e += 128 * 256) {
      float2 f = ((const float2*)fr1w)[e];
      unsigned lo = (unsigned)(unsigned short)f2bf(f.x);
      unsigned hi = (unsigned)(unsigned short)f2bf(f.y);
      ((unsigned*)wfr1)[e] = (hi << 16) | lo;
    }
    return;
  }

  short* inT = (short*)smem;             // conv1 out, padded, ch-padded to 40
  short* tile1 = (short*)(smem + 25920); // conv1 input bf16 [34][34][4] + pad
  short* inT3 = (short*)(smem + 25920);  // conv2 out (phase 2+), aliases tile1

  const int b = bx - 128;
  const int wid = tid >> 6, lane = tid & 63, q = lane >> 4, n = lane & 15;

  // ---- phase 0: issue x loads; zero halos only; scatter x -> tile1 interior
  const float* xb = x + b * 3072;
  f32x4 xf[3];
#pragma unroll
  for (int k = 0; k < 3; ++k) xf[k] = ((const f32x4*)xb)[tid + 256 * k];
  // inT halo ring (68 cells), ch 0..31 (pad ch never read): 1088 int writes
  for (int i = tid; i < 1088; i += 256) {
    int cidx = i >> 4, w = i & 15, r, cc;
    if (cidx < 18) { r = 0; cc = cidx; }
    else if (cidx < 36) { r = 17; cc = cidx - 18; }
    else { int j = cidx - 36; r = 1 + (j >> 1); cc = (j & 1) * 17; }
    ((int*)&inT[(r * 18 + cc) * 40])[w] = 0;
  }
  // tile1 halo ring (132 cells, 2 ints each) + 8-int tail pad
  for (int i = tid; i < 264; i += 256) {
    int cidx = i >> 1, w = i & 1, r, cc;
    if (cidx < 34) { r = 0; cc = cidx; }
    else if (cidx < 68) { r = 33; cc = cidx - 34; }
    else { int j = cidx - 68; r = 1 + (j >> 1); cc = (j & 1) * 33; }
    ((int*)&tile1[(r * 34 + cc) * 4])[w] = 0;
  }
  if (tid < 8) ((int*)tile1)[2312 + tid] = 0; // guard pad past row 33
  __syncthreads();
#pragma unroll
  for (int k = 0; k < 3; ++k) {
    int e0 = (tid + 256 * k) * 4;
#pragma unroll
    for (int jj = 0; jj < 4; ++jj) {
      int e = e0 + jj;
      int c = e >> 10, rem = e & 1023, iy = rem >> 5, ix = rem & 31;
      tile1[((iy + 1) * 34 + (ix + 1)) * 4 + c] = f2bf(xf[k][jj]);
    }
  }
  __syncthreads();

  // ---- phase 1: conv1 via tap-packed MFMA + shift + ReLU + maxpool2 -> inT
  {
    const short8* wv1 = (const short8*)wp1;
    short8 a00 = wv1[0 * 64 + lane]; // mf0 (ky 0,1), ct0
    short8 a01 = wv1[1 * 64 + lane]; // mf0, ct1
    short8 a10 = wv1[2 * 64 + lane]; // mf1 (ky 2), ct0
    short8 a11 = wv1[3 * 64 + lane]; // mf1, ct1
    const int ky0 = q >> 1, kx0 = (q & 1) * 2;
    float sh1[2][4];
#pragma unroll
    for (int ct = 0; ct < 2; ++ct)
#pragma unroll
      for (int r = 0; r < 4; ++r) sh1[ct][r] = scsh[384 + ct * 16 + q * 4 + r];

#pragma unroll
    for (int h = 0; h < 2; ++h) {
      const int xb0 = h * 16 + n;
#pragma unroll
      for (int yh = 0; yh < 2; ++yh) {
        f32x4 acc[2][4]; // [ct][yy]
#pragma unroll
        for (int ct = 0; ct < 2; ++ct)
#pragma unroll
          for (int yy = 0; yy < 4; ++yy) acc[ct][yy] = (f32x4)0.f;
#pragma unroll
        for (int yy = 0; yy < 4; ++yy) {
          int y = 8 * wid + yh * 4 + yy;
          const short* p0 = &tile1[((y + ky0) * 34 + xb0 + kx0) * 4];
          const short* p1 = &tile1[((y + 2) * 34 + xb0 + kx0) * 4];
          s16x4 b0l = *(const s16x4*)p0, b0h = *(const s16x4*)(p0 + 4);
          s16x4 b1l = *(const s16x4*)p1, b1h = *(const s16x4*)(p1 + 4);
          short8 B0 = __builtin_shufflevector(b0l, b0h, 0, 1, 2, 3, 4, 5, 6, 7);
          short8 B1 = __builtin_shufflevector(b1l, b1h, 0, 1, 2, 3, 4, 5, 6, 7);
          acc[0][yy] = __builtin_amdgcn_mfma_f32_16x16x32_bf16(a00, B0, acc[0][yy], 0, 0, 0);
          acc[0][yy] = __builtin_amdgcn_mfma_f32_16x16x32_bf16(a10, B1, acc[0][yy], 0, 0, 0);
          acc[1][yy] = __builtin_amdgcn_mfma_f32_16x16x32_bf16(a01, B0, acc[1][yy], 0, 0, 0);
          acc[1][yy] = __builtin_amdgcn_mfma_f32_16x16x32_bf16(a11, B1, acc[1][yy], 0, 0, 0);
        }
        // shift + ReLU + 2x2 maxpool -> inT interior
#pragma unroll
        for (int ct = 0; ct < 2; ++ct)
#pragma unroll
          for (int yp = 0; yp < 2; ++yp)
#pragma unroll
            for (int r = 0; r < 4; ++r) {
              float v0 = fmaxf(acc[ct][2 * yp][r] + sh1[ct][r], 0.f);
              float v1 = fmaxf(acc[ct][2 * yp + 1][r] + sh1[ct][r], 0.f);
              float m = fmaxf(v0, v1);
              m = fmaxf(m, __shfl_xor(m, 1));
              if ((n & 1) == 0) {
                int co = ct * 16 + q * 4 + r;
                int yq = 4 * wid + yh * 2 + yp, xq = 8 * h + (n >> 1);
                inT[((yq + 1) * 18 + (xq + 1)) * 40 + co] = f2bf(m);
              }
            }
      }
    }
  }
  __syncthreads();

  // ---- phase 2: zero inT3 halo (36 cells, ch 0..63) — tile1 is dead now
  for (int i = tid; i < 1152; i += 256) {
    int cidx = i >> 5, w = i & 31, r, cc;
    if (cidx < 10) { r = 0; cc = cidx; }
    else if (cidx < 20) { r = 9; cc = cidx - 10; }
    else { int j = cidx - 20; r = 1 + (j >> 1); cc = (j & 1) * 9; }
    ((int*)&inT3[(r * 10 + cc) * 72])[w] = 0;
  }
  __syncthreads();

  // ---- phase 3: conv2 MFMA + BN + ReLU + maxpool2 -> inT3 interior (bf16)
  {
    const short8* wv = (const short8*)wp2;
    f32x4 acc[4][4]; // [t][ct]
#pragma unroll
    for (int t = 0; t < 4; ++t)
#pragma unroll
      for (int ct = 0; ct < 4; ++ct) acc[t][ct] = (f32x4)0.f;

#pragma unroll
    for (int off = 0; off < 9; ++off) {
      const int ky = off / 3, kx = off % 3;
      short8 a[4];
#pragma unroll
      for (int ct = 0; ct < 4; ++ct) a[ct] = wv[(off * 4 + ct) * 64 + lane];
#pragma unroll
      for (int t = 0; t < 4; ++t) {
        int y = 4 * wid + t;
        short8 bf = *(const short8*)&inT[((y + ky) * 18 + (n + kx)) * 40 + q * 8];
#pragma unroll
        for (int ct = 0; ct < 4; ++ct)
          acc[t][ct] = __builtin_amdgcn_mfma_f32_16x16x32_bf16(a[ct], bf,
                                                               acc[t][ct], 0, 0, 0);
      }
    }

    const float* sc2 = scsh;
    const float* sh2 = scsh + 64;
#pragma unroll
    for (int ct = 0; ct < 4; ++ct) {
      float vm[4][4];
#pragma unroll
      for (int t = 0; t < 4; ++t)
#pragma unroll
        for (int r = 0; r < 4; ++r) {
          int co = ct * 16 + q * 4 + r;
          float v = fmaf(sc2[co], acc[t][ct][r], sh2[co]);
          v = fmaxf(v, 0.f);
          vm[t][r] = fmaxf(v, __shfl_xor(v, 1));
        }
#pragma unroll
      for (int pp = 0; pp < 2; ++pp)
#pragma unroll
        for (int r = 0; r < 4; ++r) {
          float m = fmaxf(vm[2 * pp][r], vm[2 * pp + 1][r]);
          if ((n & 1) == 0) {
            int co = ct * 16 + q * 4 + r;
            int y2 = 2 * wid + pp, x2 = n >> 1;
            inT3[((y2 + 1) * 10 + (x2 + 1)) * 72 + co] = f2bf(m);
          }
        }
    }
  }
  __syncthreads();

  // ---- phase 4: conv3 MFMA + BN + ReLU + avgpool2 -> out3 [B,2048]
  {
    const short8* wv = (const short8*)wp3;
    f32x4 acc[4][2]; // [c][tt]
#pragma unroll
    for (int c = 0; c < 4; ++c)
#pragma unroll
      for (int tt = 0; tt < 2; ++tt) acc[c][tt] = (f32x4)0.f;

    const int ct0 = (wid >> 1) * 4;
    const int t0 = (wid & 1) * 2;
#pragma unroll
    for (int off = 0; off < 9; ++off) {
      const int ky = off / 3, kx = off % 3;
#pragma unroll
      for (int half = 0; half < 2; ++half) {
        short8 a[4];
#pragma unroll
        for (int c = 0; c < 4; ++c)
          a[c] = wv[((off * 2 + half) * 8 + ct0 + c) * 64 + lane];
#pragma unroll
        for (int tt = 0; tt < 2; ++tt) {
          int y = 2 * (t0 + tt) + (n >> 3), xx = n & 7;
          short8 bf = *(const short8*)&inT3[((y + ky) * 10 + (xx + kx)) * 72 +
                                            half * 32 + q * 8];
#pragma unroll
          for (int c = 0; c < 4; ++c)
            acc[c][tt] = __builtin_amdgcn_mfma_f32_16x16x32_bf16(a[c], bf,
                                                                 acc[c][tt], 0, 0, 0);
        }
      }
    }

    const float* sc3 = scsh + 128;
    const float* sh3 = scsh + 256;
#pragma unroll
    for (int c = 0; c < 4; ++c) {
      int ct = ct0 + c;
#pragma unroll
      for (int tt = 0; tt < 2; ++tt) {
        int t = t0 + tt;
#pragma unroll
        for (int r = 0; r < 4; ++r) {
          int co = ct * 16 + q * 4 + r;
          float v = fmaf(sc3[co], acc[c][tt][r], sh3[co]);
          v = fmaxf(v, 0.f);
          float s = v + __shfl_xor(v, 1);
          s += __shfl_xor(s, 8);
          if ((n & 9) == 0)
            out3[(size_t)b * 2048 + co * 16 + t * 4 + (n >> 1)] = f2bf(s * 0.25f);
        }
      }
    }
  }
}

// ---------------- fr1 (MFMA): [1024,2048]bf16 x [512,2048]bf16^T +bias,ReLU ->
// f32 [1024,512]. 32x32 tile/block, BK=64, double-buffered LDS + reg prefetch
// (one barrier per K-step; global-load latency hidden under MFMA+barrier). ---
__global__ __launch_bounds__(256) void k_fr1m(
    const short* __restrict__ A, const short* __restrict__ W,
    const float* __restrict__ bias, float* __restrict__ C) {
  __shared__ __align__(16) short As[2 * 2304];
  __shared__ __align__(16) short Bs[2 * 2304];
  const int m0 = blockIdx.x * 32;
  const int n0 = blockIdx.y * 32;
  const int tid = threadIdx.x;
  const int w = tid >> 6, lane = tid & 63, q = lane >> 4, n = lane & 15;
  const int mt = w >> 1, nt = w & 1;
  const int srow = tid >> 3, sc = tid & 7;

  f32x4 acc = (f32x4)0.f;
  const short* Ab = A + (size_t)(m0 + srow) * 2048 + sc * 8;
  const short* Wb = W + (size_t)(n0 + srow) * 2048 + sc * 8;

  short8 av = *(const short8*)Ab;
  short8 bv = *(const short8*)Wb;
  for (int it = 0; it < 32; ++it) {
    short* Asb = As + (it & 1) * 2304;
    short* Bsb = Bs + (it & 1) * 2304;
    *(short8*)&Asb[srow * 72 + sc * 8] = av;
    *(short8*)&Bsb[srow * 72 + sc * 8] = bv;
    if (it < 31) {
      av = *(const short8*)(Ab + (it + 1) * 64);
      bv = *(const short8*)(Wb + (it + 1) * 64);
    }
    __syncthreads();
#pragma unroll
    for (int kk = 0; kk < 2; ++kk) {
      short8 bfrag = *(const short8*)&Bsb[(nt * 16 + n) * 72 + kk * 32 + q * 8];
      short8 afrag = *(const short8*)&Asb[(mt * 16 + n) * 72 + kk * 32 + q * 8];
      acc = __builtin_amdgcn_mfma_f32_16x16x32_bf16(afrag, bfrag, acc, 0, 0, 0);
    }
  }
#pragma unroll
  for (int r = 0; r < 4; ++r) {
    int m = m0 + mt * 16 + q * 4 + r;
    int nn = n0 + nt * 16 + n;
    C[(size_t)m * 512 + nn] = fmaxf(acc[r] + bias[nn], 0.f);
  }
}

// ---------------- tail: fr2 + softmax + quantum + head ----------------------
__global__ __launch_bounds__(64) void k_tail(
    const float* __restrict__ H, const float* __restrict__ W2,
    const float* __restrict__ b2, const float* __restrict__ qw,
    const float* __restrict__ h1w, const float* __restrict__ h1b,
    const float* __restrict__ bg, const float* __restrict__ bb,
    const float* __restrict__ h2w, const float* __restrict__ h2b,
    float* __restrict__ out) {
  __shared__ float hbuf[512];
  __shared__ float ybuf[128];
  const int b = blockIdx.x;
  const int lane = threadIdx.x;
  const float* hrow = H + b * 512;
  *(float4*)&hbuf[lane * 4] = *(const float4*)&hrow[lane * 4];
  *(float4*)&hbuf[256 + lane * 4] = *(const float4*)&hrow[256 + lane * 4];
  __syncthreads();

  const int j = lane & 15;
  const int grpk = lane >> 4;
  float partial = 0.f;
  const float* wrow = W2 + j * 512 + grpk * 128;
  const float* hb = hbuf + grpk * 128;
#pragma unroll
  for (int k = 0; k < 128; k += 4) {
    float4 wv = *(const float4*)&wrow[k];
    partial = fmaf(wv.x, hb[k + 0], partial);
    partial = fmaf(wv.y, hb[k + 1], partial);
    partial = fmaf(wv.z, hb[k + 2], partial);
    partial = fmaf(wv.w, hb[k + 3], partial);
  }
  partial += __shfl_xor(partial, 16);
  partial += __shfl_xor(partial, 32);
  float logit = partial + b2[j];

  float m = logit;
#pragma unroll
  for (int d = 1; d < 16; d <<= 1) m = fmaxf(m, __shfl_xor(m, d));
  float e = expf(logit - m);
  float s = e;
#pragma unroll
  for (int d = 1; d < 16; d <<= 1) s += __shfl_xor(s, d);
  float p = e / s;

  float n2 = p * p;
#pragma unroll
  for (int d = 1; d < 16; d <<= 1) n2 += __shfl_xor(n2, d);
  float amp = p / sqrtf(n2);
  float re = amp, im = 0.f;

#pragma unroll
  for (int l = 0; l < 2; ++l) {
#pragma unroll
    for (int q = 0; q < 4; ++q) {
      float th = qw[l * 4 + q] * 0.5f;
      float c = cosf(th), sn = sinf(th);
      int mask = 1 << (3 - q);
      float pre = __shfl_xor(re, mask);
      float pim = __shfl_xor(im, mask);
      float nre = fmaf(c, re, sn * pim);
      float nim = fmaf(c, im, -sn * pre);
      re = nre;
      im = nim;
    }
    int src = j;
    if (src & 1) src ^= 8;
    if (src & 2) src ^= 1;
    if (src & 4) src ^= 2;
    if (src & 8) src ^= 4;
    int srclane = (lane & 48) | src;
    re = __shfl(re, srclane);
    im = __shfl(im, srclane);
  }

  float prob = re * re + im * im;
  float qv[4];
#pragma unroll
  for (int w = 0; w < 4; ++w) {
    float sgn = ((j >> (3 - w)) & 1) ? -1.f : 1.f;
    float cwv = prob * sgn;
    cwv += __shfl_xor(cwv, 1);
    cwv += __shfl_xor(cwv, 2);
    cwv += __shfl_xor(cwv, 4);
    cwv += __shfl_xor(cwv, 8);
    qv[w] = cwv;
  }

#pragma unroll
  for (int t = 0; t < 2; ++t) {
    int jj = lane + 64 * t;
    float4 hw = *(const float4*)&h1w[jj * 4];
    float y = h1b[jj];
    y = fmaf(hw.x, qv[0], y);
    y = fmaf(hw.y, qv[1], y);
    y = fmaf(hw.z, qv[2], y);
    y = fmaf(hw.w, qv[3], y);
    y = fmaf(bg[jj] * BN_INV, y, bb[jj]);
    ybuf[jj] = fmaxf(y, 0.f);
  }
  __syncthreads();

#pragma unroll
  for (int t = 0; t < 2; ++t) {
    int k = lane + 64 * t;
    if (k < 100) {
      const float* wr = h2w + k * 128;
      float o = h2b[k];
#pragma unroll
      for (int jj = 0; jj < 128; jj += 4) {
        float4 wv = *(const float4*)&wr[jj];
        o = fmaf(wv.x, ybuf[jj + 0], o);
        o = fmaf(wv.y, ybuf[jj + 1], o);
        o = fmaf(wv.z, ybuf[jj + 2], o);
        o = fmaf(wv.w, ybuf[jj + 3], o);
      }
      out[b * 100 + k] = o;
    }
  }
}

extern "C" void kernel_launch(void* const* d_in, const int* in_sizes, int n_in,
                              void* d_out, int out_size, void* d_ws,
                              size_t ws_size, hipStream_t stream) {
  const float* x = (const float*)d_in[0];
  const float* c1w = (const float*)d_in[1];
  const float* c1b = (const float*)d_in[2];
  const float* g1 = (const float*)d_in[3];
  const float* be1 = (const float*)d_in[4];
  const float* c2w = (const float*)d_in[5];
  const float* c2b = (const float*)d_in[6];
  const float* g2 = (const float*)d_in[7];
  const float* be2 = (const float*)d_in[8];
  const float* c3w = (const float*)d_in[9];
  const float* c3b = (const float*)d_in[10];
  const float* g3 = (const float*)d_in[11];
  const float* be3 = (const float*)d_in[12];
  const float* fr1w = (const float*)d_in[13];
  const float* fr1b = (const float*)d_in[14];
  const float* fr2w = (const float*)d_in[15];
  const float* fr2b = (const float*)d_in[16];
  const float* qwts = (const float*)d_in[17];
  const float* h1w = (const float*)d_in[18];
  const float* h1b = (const float*)d_in[19];
  const float* bhg = (const float*)d_in[20];
  const float* bhb = (const float*)d_in[21];
  const float* h2w = (const float*)d_in[22];
  const float* h2b = (const float*)d_in[23];
  float* out = (float*)d_out;

  float* ws = (float*)d_ws;
  // layout (float offsets), total ~8.6 MB:
  //   out3bf [0, 1048576)          bf16 [1024,2048]
  //   h1     [1048576, 1572864)    f32  [1024,512]
  //   wfr1   [1572864, 2097152)    bf16 [512,2048]
  //   wp2    [2097152, +9216)      bf16 18432
  //   wp3    [2106368, +36864)     bf16 73728
  //   scsh   [2143232, +512)       f32 416 used
  //   wp1    [2143744, +1024)      bf16 2048 (tap-packed)
  short* out3bf = (short*)ws;
  float* h1 = ws + 1048576;
  short* wfr1 = (short*)(ws + 1572864);
  short* wp2 = (short*)(ws + 2097152);
  short* wp3 = (short*)(ws + 2106368);
  float* scsh = ws + 2143232;
  short* wp1 = (short*)(ws + 2143744);

  k_prepack<<<96, 256, 0, stream>>>(c1w, c1b, g1, be1, c2w, c2b, g2, be2, c3w,
                                    c3b, g3, be3, wp1, wp2, wp3, scsh);
  k_convfused<<<NB + 128, 256, 0, stream>>>(x, wp1, wp2, wp3, scsh, fr1w, wfr1,
                                            out3bf);
  k_fr1m<<<dim3(32, 16), 256, 0, stream>>>(out3bf, wfr1, fr1b, h1);
  k_tail<<<NB, 64, 0, stream>>>(h1, fr2w, fr2b, qwts, h1w, h1b, bhg, bhb, h2w,
                                h2b, out);
}

// Round 6
// 166.046 us; speedup vs baseline: 1.8305x; 1.0733x over previous
//
#include <hip/hip_runtime.h>
#include <math.h>

#define NB 1024
static constexpr float BN_INV = 0.99999500003749975f; // 1/sqrt(1+1e-5)

typedef __attribute__((ext_vector_type(8))) short short8;
typedef __attribute__((ext_vector_type(4))) short s16x4;
typedef __attribute__((ext_vector_type(4))) float f32x4;

__device__ inline short f2bf(float f) {
  union { float f; unsigned u; } v;
  v.f = f;
  unsigned u = v.u;
  u += 0x7fff + ((u >> 16) & 1); // RNE
  return (short)(u >> 16);
}

// ---------------- prepack: conv weights -> MFMA A-frag bf16, BN folded ------
// conv1 K-packed: mf0: k = ky*16 + kx*4 + c (ky 0..1, kx 0..3 pad, c 0..3 pad)
//                 mf1: k = kx*4 + c, ky=2 (k>=16 zero)
// scale folded into conv1 weights; shift into scsh[384..416).
__global__ void k_prepack(const float* __restrict__ c1w, const float* __restrict__ c1b,
                          const float* __restrict__ g1, const float* __restrict__ be1,
                          const float* __restrict__ c2w, const float* __restrict__ c2b,
                          const float* __restrict__ g2, const float* __restrict__ be2,
                          const float* __restrict__ c3w, const float* __restrict__ c3b,
                          const float* __restrict__ g3, const float* __restrict__ be3,
                          short* __restrict__ wp1, short* __restrict__ wp2,
                          short* __restrict__ wp3, float* __restrict__ scsh) {
  int i = blockIdx.x * 256 + threadIdx.x;
  int stride = gridDim.x * 256;
  // conv1 A-frags: 2 mf x 2 ct x 64 lanes x 8 = 2048 bf16
  for (int e = i; e < 2048; e += stride) {
    int j = e & 7, lane = (e >> 3) & 63, ct = (e >> 9) & 1, mf = e >> 10;
    int co = ct * 16 + (lane & 15), k = (lane >> 4) * 8 + j;
    int kx = (k >> 2) & 3, c = k & 3;
    float v = 0.f;
    if (mf == 0) {
      int ky = k >> 4;
      if (kx < 3 && c < 3) v = c1w[(co * 3 + c) * 9 + ky * 3 + kx] * g1[co] * BN_INV;
    } else {
      if (k < 16 && kx < 3 && c < 3)
        v = c1w[(co * 3 + c) * 9 + 6 + kx] * g1[co] * BN_INV;
    }
    wp1[e] = f2bf(v);
  }
  for (int e = i; e < 18432; e += stride) {
    int j = e & 7, lane = (e >> 3) & 63, ct = (e >> 9) & 3, off = e >> 11;
    int co = ct * 16 + (lane & 15), ci = (lane >> 4) * 8 + j;
    wp2[e] = f2bf(c2w[(co * 32 + ci) * 9 + off]);
  }
  for (int e = i; e < 73728; e += stride) {
    int j = e & 7, lane = (e >> 3) & 63, ct = (e >> 9) & 7, oh = e >> 12;
    int half = oh & 1, off = oh >> 1;
    int co = ct * 16 + (lane & 15), ci = half * 32 + (lane >> 4) * 8 + j;
    wp3[e] = f2bf(c3w[(co * 64 + ci) * 9 + off]);
  }
  if (i < 64) {
    float sc = g2[i] * BN_INV;
    scsh[i] = sc;
    scsh[64 + i] = sc * c2b[i] + be2[i];
  } else if (i < 192) {
    int c = i - 64;
    float sc = g3[c] * BN_INV;
    scsh[128 + c] = sc;
    scsh[256 + c] = sc * c3b[c] + be3[c];
  } else if (i < 224) {
    int c = i - 192;
    scsh[384 + c] = g1[c] * BN_INV * c1b[c] + be1[c];
  }
}

// ---------------- fused conv1+conv2+conv3: 512 threads (8 waves), 3 barriers.
// Blocks [0,128): fr1_w f32->bf16 conversion (dispatched first, overlaps).
// Blocks [128,1152): conv pipeline, all intermediates in LDS.
// LDS (no aliasing): inT [18*18][40] 25920 B | tile1 [34*34][4]+pad 9280 B |
//                    inT3 [10*10][72] 14400 B  = 49600 B total.
// All halo zeroing hoisted to phase 0 (tile1/inT3 disjoint from writers).
__global__ __launch_bounds__(512) void k_convfused(
    const float* __restrict__ x, const short* __restrict__ wp1,
    const short* __restrict__ wp2, const short* __restrict__ wp3,
    const float* __restrict__ scsh, const float* __restrict__ fr1w,
    short* __restrict__ wfr1, short* __restrict__ out3 /* bf16 [B,2048] */) {
  __shared__ __align__(16) char smem[49600];
  const int tid = threadIdx.x;
  const int bx = blockIdx.x;

  if (bx < 128) {
    // fr1_w: 512*2048 f32 -> bf16, two at a time, 128 blocks x 512 thr
    int i = bx * 512 + tid;
    for (int e = i; e < 524288; e += 128 * 512) {
      float2 f = ((const float2*)fr1w)[e];
      unsigned lo = (unsigned)(unsigned short)f2bf(f.x);
      unsigned hi = (unsigned)(unsigned short)f2bf(f.y);
      ((unsigned*)wfr1)[e] = (hi << 16) | lo;
    }
    return;
  }

  short* inT = (short*)smem;             // conv1 out, padded, ch-padded to 40
  short* tile1 = (short*)(smem + 25920); // conv1 input bf16 [34][34][4] + pad
  short* inT3 = (short*)(smem + 35200);  // conv2 out [10][10][72]

  const int b = bx - 128;
  const int wid = tid >> 6, lane = tid & 63, q = lane >> 4, n = lane & 15;

  // ---- phase 0: issue x loads; zero ALL halos; scatter x -> tile1 interior
  const float* xb = x + b * 3072;
  f32x4 xf0 = ((const f32x4*)xb)[tid];
  f32x4 xf1;
  if (tid < 256) xf1 = ((const f32x4*)xb)[tid + 512];
  // inT halo ring (68 cells), ch 0..31: 1088 int writes
  for (int i = tid; i < 1088; i += 512) {
    int cidx = i >> 4, w = i & 15, r, cc;
    if (cidx < 18) { r = 0; cc = cidx; }
    else if (cidx < 36) { r = 17; cc = cidx - 18; }
    else { int j = cidx - 36; r = 1 + (j >> 1); cc = (j & 1) * 17; }
    ((int*)&inT[(r * 18 + cc) * 40])[w] = 0;
  }
  // tile1 halo ring (132 cells, 2 ints each)
  for (int i = tid; i < 264; i += 512) {
    int cidx = i >> 1, w = i & 1, r, cc;
    if (cidx < 34) { r = 0; cc = cidx; }
    else if (cidx < 68) { r = 33; cc = cidx - 34; }
    else { int j = cidx - 68; r = 1 + (j >> 1); cc = (j & 1) * 33; }
    ((int*)&tile1[(r * 34 + cc) * 4])[w] = 0;
  }
  if (tid < 8) ((int*)tile1)[2312 + tid] = 0; // guard pad past row 33
  // inT3 halo ring (36 cells, ch 0..63): 1152 int writes
  for (int i = tid; i < 1152; i += 512) {
    int cidx = i >> 5, w = i & 31, r, cc;
    if (cidx < 10) { r = 0; cc = cidx; }
    else if (cidx < 20) { r = 9; cc = cidx - 10; }
    else { int j = cidx - 20; r = 1 + (j >> 1); cc = (j & 1) * 9; }
    ((int*)&inT3[(r * 10 + cc) * 72])[w] = 0;
  }
  // scatter x interior (disjoint from all halo writes -> no barrier needed yet)
  {
    int e0 = tid * 4;
#pragma unroll
    for (int jj = 0; jj < 4; ++jj) {
      int e = e0 + jj;
      int c = e >> 10, rem = e & 1023, iy = rem >> 5, ix = rem & 31;
      tile1[((iy + 1) * 34 + (ix + 1)) * 4 + c] = f2bf(xf0[jj]);
    }
    if (tid < 256) {
      int e1 = (tid + 512) * 4;
#pragma unroll
      for (int jj = 0; jj < 4; ++jj) {
        int e = e1 + jj;
        int c = e >> 10, rem = e & 1023, iy = rem >> 5, ix = rem & 31;
        tile1[((iy + 1) * 34 + (ix + 1)) * 4 + c] = f2bf(xf1[jj]);
      }
    }
  }
  __syncthreads(); // barrier 1

  // ---- phase 1: conv1 via tap-packed MFMA + shift + ReLU + maxpool2 -> inT
  {
    const short8* wv1 = (const short8*)wp1;
    short8 a00 = wv1[0 * 64 + lane]; // mf0 (ky 0,1), ct0
    short8 a01 = wv1[1 * 64 + lane]; // mf0, ct1
    short8 a10 = wv1[2 * 64 + lane]; // mf1 (ky 2), ct0
    short8 a11 = wv1[3 * 64 + lane]; // mf1, ct1
    const int ky0 = q >> 1, kx0 = (q & 1) * 2;
    float sh1[2][4];
#pragma unroll
    for (int ct = 0; ct < 2; ++ct)
#pragma unroll
      for (int r = 0; r < 4; ++r) sh1[ct][r] = scsh[384 + ct * 16 + q * 4 + r];

#pragma unroll
    for (int h = 0; h < 2; ++h) {
      const int xb0 = h * 16 + n;
      f32x4 acc[2][4]; // [ct][yy], y = 4*wid + yy
#pragma unroll
      for (int ct = 0; ct < 2; ++ct)
#pragma unroll
        for (int yy = 0; yy < 4; ++yy) acc[ct][yy] = (f32x4)0.f;
#pragma unroll
      for (int yy = 0; yy < 4; ++yy) {
        int y = 4 * wid + yy;
        const short* p0 = &tile1[((y + ky0) * 34 + xb0 + kx0) * 4];
        const short* p1 = &tile1[((y + 2) * 34 + xb0 + kx0) * 4];
        s16x4 b0l = *(const s16x4*)p0, b0h = *(const s16x4*)(p0 + 4);
        s16x4 b1l = *(const s16x4*)p1, b1h = *(const s16x4*)(p1 + 4);
        short8 B0 = __builtin_shufflevector(b0l, b0h, 0, 1, 2, 3, 4, 5, 6, 7);
        short8 B1 = __builtin_shufflevector(b1l, b1h, 0, 1, 2, 3, 4, 5, 6, 7);
        acc[0][yy] = __builtin_amdgcn_mfma_f32_16x16x32_bf16(a00, B0, acc[0][yy], 0, 0, 0);
        acc[0][yy] = __builtin_amdgcn_mfma_f32_16x16x32_bf16(a10, B1, acc[0][yy], 0, 0, 0);
        acc[1][yy] = __builtin_amdgcn_mfma_f32_16x16x32_bf16(a01, B0, acc[1][yy], 0, 0, 0);
        acc[1][yy] = __builtin_amdgcn_mfma_f32_16x16x32_bf16(a11, B1, acc[1][yy], 0, 0, 0);
      }
      // shift + ReLU + 2x2 maxpool -> inT interior
#pragma unroll
      for (int ct = 0; ct < 2; ++ct)
#pragma unroll
        for (int yp = 0; yp < 2; ++yp)
#pragma unroll
          for (int r = 0; r < 4; ++r) {
            float v0 = fmaxf(acc[ct][2 * yp][r] + sh1[ct][r], 0.f);
            float v1 = fmaxf(acc[ct][2 * yp + 1][r] + sh1[ct][r], 0.f);
            float m = fmaxf(v0, v1);
            m = fmaxf(m, __shfl_xor(m, 1));
            if ((n & 1) == 0) {
              int co = ct * 16 + q * 4 + r;
              int yq = 2 * wid + yp, xq = 8 * h + (n >> 1);
              inT[((yq + 1) * 18 + (xq + 1)) * 40 + co] = f2bf(m);
            }
          }
    }
  }
  __syncthreads(); // barrier 2

  // ---- phase 2: conv2 MFMA + BN + ReLU + maxpool2 -> inT3 interior (bf16)
  {
    const short8* wv = (const short8*)wp2;
    f32x4 acc[2][4]; // [t][ct], rows y = 2*wid + t
#pragma unroll
    for (int t = 0; t < 2; ++t)
#pragma unroll
      for (int ct = 0; ct < 4; ++ct) acc[t][ct] = (f32x4)0.f;

#pragma unroll
    for (int off = 0; off < 9; ++off) {
      const int ky = off / 3, kx = off % 3;
      short8 a[4];
#pragma unroll
      for (int ct = 0; ct < 4; ++ct) a[ct] = wv[(off * 4 + ct) * 64 + lane];
#pragma unroll
      for (int t = 0; t < 2; ++t) {
        int y = 2 * wid + t;
        short8 bf = *(const short8*)&inT[((y + ky) * 18 + (n + kx)) * 40 + q * 8];
#pragma unroll
        for (int ct = 0; ct < 4; ++ct)
          acc[t][ct] = __builtin_amdgcn_mfma_f32_16x16x32_bf16(a[ct], bf,
                                                               acc[t][ct], 0, 0, 0);
      }
    }

    const float* sc2 = scsh;
    const float* sh2 = scsh + 64;
#pragma unroll
    for (int ct = 0; ct < 4; ++ct)
#pragma unroll
      for (int r = 0; r < 4; ++r) {
        int co = ct * 16 + q * 4 + r;
        float v0 = fmaf(sc2[co], acc[0][ct][r], sh2[co]);
        float v1 = fmaf(sc2[co], acc[1][ct][r], sh2[co]);
        v0 = fmaxf(v0, 0.f);
        v1 = fmaxf(v1, 0.f);
        float m0 = fmaxf(v0, __shfl_xor(v0, 1));
        float m1 = fmaxf(v1, __shfl_xor(v1, 1));
        float m = fmaxf(m0, m1);
        if ((n & 1) == 0)
          inT3[((wid + 1) * 10 + (n >> 1) + 1) * 72 + co] = f2bf(m);
      }
  }
  __syncthreads(); // barrier 3

  // ---- phase 3: conv3 MFMA + BN + ReLU + avgpool2 -> out3 [B,2048]
  {
    const short8* wv = (const short8*)wp3;
    f32x4 acc[2][2]; // [c][tt]
#pragma unroll
    for (int c = 0; c < 2; ++c)
#pragma unroll
      for (int tt = 0; tt < 2; ++tt) acc[c][tt] = (f32x4)0.f;

    const int ct0 = (wid >> 1) * 2;
    const int t0 = (wid & 1) * 2;
#pragma unroll
    for (int off = 0; off < 9; ++off) {
      const int ky = off / 3, kx = off % 3;
#pragma unroll
      for (int half = 0; half < 2; ++half) {
        short8 a[2];
#pragma unroll
        for (int c = 0; c < 2; ++c)
          a[c] = wv[((off * 2 + half) * 8 + ct0 + c) * 64 + lane];
#pragma unroll
        for (int tt = 0; tt < 2; ++tt) {
          int y = 2 * (t0 + tt) + (n >> 3), xx = n & 7;
          short8 bf = *(const short8*)&inT3[((y + ky) * 10 + (xx + kx)) * 72 +
                                            half * 32 + q * 8];
#pragma unroll
          for (int c = 0; c < 2; ++c)
            acc[c][tt] = __builtin_amdgcn_mfma_f32_16x16x32_bf16(a[c], bf,
                                                                 acc[c][tt], 0, 0, 0);
        }
      }
    }

    const float* sc3 = scsh + 128;
    const float* sh3 = scsh + 256;
#pragma unroll
    for (int c = 0; c < 2; ++c) {
      int ct = ct0 + c;
#pragma unroll
      for (int tt = 0; tt < 2; ++tt) {
        int t = t0 + tt;
#pragma unroll
        for (int r = 0; r < 4; ++r) {
          int co = ct * 16 + q * 4 + r;
          float v = fmaf(sc3[co], acc[c][tt][r], sh3[co]);
          v = fmaxf(v, 0.f);
          float s = v + __shfl_xor(v, 1);
          s += __shfl_xor(s, 8);
          if ((n & 9) == 0)
            out3[(size_t)b * 2048 + co * 16 + t * 4 + (n >> 1)] = f2bf(s * 0.25f);
        }
      }
    }
  }
}

// ---------------- fr1 (MFMA): [1024,2048]bf16 x [512,2048]bf16^T +bias,ReLU ->
// f32 [1024,512]. 32x32 tile/block, BK=64, double-buffered LDS + reg prefetch.
__global__ __launch_bounds__(256) void k_fr1m(
    const short* __restrict__ A, const short* __restrict__ W,
    const float* __restrict__ bias, float* __restrict__ C) {
  __shared__ __align__(16) short As[2 * 2304];
  __shared__ __align__(16) short Bs[2 * 2304];
  const int m0 = blockIdx.x * 32;
  const int n0 = blockIdx.y * 32;
  const int tid = threadIdx.x;
  const int w = tid >> 6, lane = tid & 63, q = lane >> 4, n = lane & 15;
  const int mt = w >> 1, nt = w & 1;
  const int srow = tid >> 3, sc = tid & 7;

  f32x4 acc = (f32x4)0.f;
  const short* Ab = A + (size_t)(m0 + srow) * 2048 + sc * 8;
  const short* Wb = W + (size_t)(n0 + srow) * 2048 + sc * 8;

  short8 av = *(const short8*)Ab;
  short8 bv = *(const short8*)Wb;
  for (int it = 0; it < 32; ++it) {
    short* Asb = As + (it & 1) * 2304;
    short* Bsb = Bs + (it & 1) * 2304;
    *(short8*)&Asb[srow * 72 + sc * 8] = av;
    *(short8*)&Bsb[srow * 72 + sc * 8] = bv;
    if (it < 31) {
      av = *(const short8*)(Ab + (it + 1) * 64);
      bv = *(const short8*)(Wb + (it + 1) * 64);
    }
    __syncthreads();
#pragma unroll
    for (int kk = 0; kk < 2; ++kk) {
      short8 bfrag = *(const short8*)&Bsb[(nt * 16 + n) * 72 + kk * 32 + q * 8];
      short8 afrag = *(const short8*)&Asb[(mt * 16 + n) * 72 + kk * 32 + q * 8];
      acc = __builtin_amdgcn_mfma_f32_16x16x32_bf16(afrag, bfrag, acc, 0, 0, 0);
    }
  }
#pragma unroll
  for (int r = 0; r < 4; ++r) {
    int m = m0 + mt * 16 + q * 4 + r;
    int nn = n0 + nt * 16 + n;
    C[(size_t)m * 512 + nn] = fmaxf(acc[r] + bias[nn], 0.f);
  }
}

// ---------------- tail: fr2 + softmax + quantum + head ----------------------
__global__ __launch_bounds__(64) void k_tail(
    const float* __restrict__ H, const float* __restrict__ W2,
    const float* __restrict__ b2, const float* __restrict__ qw,
    const float* __restrict__ h1w, const float* __restrict__ h1b,
    const float* __restrict__ bg, const float* __restrict__ bb,
    const float* __restrict__ h2w, const float* __restrict__ h2b,
    float* __restrict__ out) {
  __shared__ float hbuf[512];
  __shared__ float ybuf[128];
  const int b = blockIdx.x;
  const int lane = threadIdx.x;
  const float* hrow = H + b * 512;
  *(float4*)&hbuf[lane * 4] = *(const float4*)&hrow[lane * 4];
  *(float4*)&hbuf[256 + lane * 4] = *(const float4*)&hrow[256 + lane * 4];
  __syncthreads();

  const int j = lane & 15;
  const int grpk = lane >> 4;
  float partial = 0.f;
  const float* wrow = W2 + j * 512 + grpk * 128;
  const float* hb = hbuf + grpk * 128;
#pragma unroll
  for (int k = 0; k < 128; k += 4) {
    float4 wv = *(const float4*)&wrow[k];
    partial = fmaf(wv.x, hb[k + 0], partial);
    partial = fmaf(wv.y, hb[k + 1], partial);
    partial = fmaf(wv.z, hb[k + 2], partial);
    partial = fmaf(wv.w, hb[k + 3], partial);
  }
  partial += __shfl_xor(partial, 16);
  partial += __shfl_xor(partial, 32);
  float logit = partial + b2[j];

  float m = logit;
#pragma unroll
  for (int d = 1; d < 16; d <<= 1) m = fmaxf(m, __shfl_xor(m, d));
  float e = expf(logit - m);
  float s = e;
#pragma unroll
  for (int d = 1; d < 16; d <<= 1) s += __shfl_xor(s, d);
  float p = e / s;

  float n2 = p * p;
#pragma unroll
  for (int d = 1; d < 16; d <<= 1) n2 += __shfl_xor(n2, d);
  float amp = p / sqrtf(n2);
  float re = amp, im = 0.f;

#pragma unroll
  for (int l = 0; l < 2; ++l) {
#pragma unroll
    for (int q = 0; q < 4; ++q) {
      float th = qw[l * 4 + q] * 0.5f;
      float c = cosf(th), sn = sinf(th);
      int mask = 1 << (3 - q);
      float pre = __shfl_xor(re, mask);
      float pim = __shfl_xor(im, mask);
      float nre = fmaf(c, re, sn * pim);
      float nim = fmaf(c, im, -sn * pre);
      re = nre;
      im = nim;
    }
    int src = j;
    if (src & 1) src ^= 8;
    if (src & 2) src ^= 1;
    if (src & 4) src ^= 2;
    if (src & 8) src ^= 4;
    int srclane = (lane & 48) | src;
    re = __shfl(re, srclane);
    im = __shfl(im, srclane);
  }

  float prob = re * re + im * im;
  float qv[4];
#pragma unroll
  for (int w = 0; w < 4; ++w) {
    float sgn = ((j >> (3 - w)) & 1) ? -1.f : 1.f;
    float cwv = prob * sgn;
    cwv += __shfl_xor(cwv, 1);
    cwv += __shfl_xor(cwv, 2);
    cwv += __shfl_xor(cwv, 4);
    cwv += __shfl_xor(cwv, 8);
    qv[w] = cwv;
  }

#pragma unroll
  for (int t = 0; t < 2; ++t) {
    int jj = lane + 64 * t;
    float4 hw = *(const float4*)&h1w[jj * 4];
    float y = h1b[jj];
    y = fmaf(hw.x, qv[0], y);
    y = fmaf(hw.y, qv[1], y);
    y = fmaf(hw.z, qv[2], y);
    y = fmaf(hw.w, qv[3], y);
    y = fmaf(bg[jj] * BN_INV, y, bb[jj]);
    ybuf[jj] = fmaxf(y, 0.f);
  }
  __syncthreads();

#pragma unroll
  for (int t = 0; t < 2; ++t) {
    int k = lane + 64 * t;
    if (k < 100) {
      const float* wr = h2w + k * 128;
      float o = h2b[k];
#pragma unroll
      for (int jj = 0; jj < 128; jj += 4) {
        float4 wv = *(const float4*)&wr[jj];
        o = fmaf(wv.x, ybuf[jj + 0], o);
        o = fmaf(wv.y, ybuf[jj + 1], o);
        o = fmaf(wv.z, ybuf[jj + 2], o);
        o = fmaf(wv.w, ybuf[jj + 3], o);
      }
      out[b * 100 + k] = o;
    }
  }
}

extern "C" void kernel_launch(void* const* d_in, const int* in_sizes, int n_in,
                              void* d_out, int out_size, void* d_ws,
                              size_t ws_size, hipStream_t stream) {
  const float* x = (const float*)d_in[0];
  const float* c1w = (const float*)d_in[1];
  const float* c1b = (const float*)d_in[2];
  const float* g1 = (const float*)d_in[3];
  const float* be1 = (const float*)d_in[4];
  const float* c2w = (const float*)d_in[5];
  const float* c2b = (const float*)d_in[6];
  const float* g2 = (const float*)d_in[7];
  const float* be2 = (const float*)d_in[8];
  const float* c3w = (const float*)d_in[9];
  const float* c3b = (const float*)d_in[10];
  const float* g3 = (const float*)d_in[11];
  const float* be3 = (const float*)d_in[12];
  const float* fr1w = (const float*)d_in[13];
  const float* fr1b = (const float*)d_in[14];
  const float* fr2w = (const float*)d_in[15];
  const float* fr2b = (const float*)d_in[16];
  const float* qwts = (const float*)d_in[17];
  const float* h1w = (const float*)d_in[18];
  const float* h1b = (const float*)d_in[19];
  const float* bhg = (const float*)d_in[20];
  const float* bhb = (const float*)d_in[21];
  const float* h2w = (const float*)d_in[22];
  const float* h2b = (const float*)d_in[23];
  float* out = (float*)d_out;

  float* ws = (float*)d_ws;
  // layout (float offsets), total ~8.6 MB:
  //   out3bf [0, 1048576)          bf16 [1024,2048]
  //   h1     [1048576, 1572864)    f32  [1024,512]
  //   wfr1   [1572864, 2097152)    bf16 [512,2048]
  //   wp2    [2097152, +9216)      bf16 18432
  //   wp3    [2106368, +36864)     bf16 73728
  //   scsh   [2143232, +512)       f32 416 used
  //   wp1    [2143744, +1024)      bf16 2048 (tap-packed)
  short* out3bf = (short*)ws;
  float* h1 = ws + 1048576;
  short* wfr1 = (short*)(ws + 1572864);
  short* wp2 = (short*)(ws + 2097152);
  short* wp3 = (short*)(ws + 2106368);
  float* scsh = ws + 2143232;
  short* wp1 = (short*)(ws + 2143744);

  k_prepack<<<96, 256, 0, stream>>>(c1w, c1b, g1, be1, c2w, c2b, g2, be2, c3w,
                                    c3b, g3, be3, wp1, wp2, wp3, scsh);
  k_convfused<<<NB + 128, 512, 0, stream>>>(x, wp1, wp2, wp3, scsh, fr1w, wfr1,
                                            out3bf);
  k_fr1m<<<dim3(32, 16), 256, 0, stream>>>(out3bf, wfr1, fr1b, h1);
  k_tail<<<NB, 64, 0, stream>>>(h1, fr2w, fr2b, qwts, h1w, h1b, bhg, bhb, h2w,
                                h2b, out);
}